// Round 17
// baseline (134.542 us; speedup 1.0000x reference)
//
#include <hip/hip_runtime.h>

typedef unsigned short u16;
typedef unsigned int u32;
typedef short bf16x8s __attribute__((ext_vector_type(8)));
typedef float f32x4 __attribute__((ext_vector_type(4)));

#define SCALE_C 0.044194173824159216f  // 512^-0.5
#define MFMA16 __builtin_amdgcn_mfma_f32_16x16x32_bf16

__device__ __forceinline__ u16 f2bf(float f){
  union { float f; u32 u; } c; c.f = f;
  u32 u = c.u;
  return (u16)((u + 0x7fffu + ((u >> 16) & 1u)) >> 16);
}

__device__ __forceinline__ void gload16(const void* g, void* l){
  __builtin_amdgcn_global_load_lds((const __attribute__((address_space(1))) void*)g,
                                   (__attribute__((address_space(3))) void*)l, 16, 0, 0);
}

// ---------------- workspace layout (bytes) ----------------
#define OFF_KXB  ((size_t)0)                  // 32768*512*2
#define OFF_G    (OFF_KXB + 33554432)         // 256*128*128*2
#define OFF_W2B  (OFF_G + 8388608)            // 1000*2048*2
#define OFF_H    (OFF_W2B + 4096000)          // 512*2048*2
#define OFF_W1B  (OFF_H + 2097152)            // unused
#define OFF_QLN  (OFF_W1B + 2097152)
#define OFF_QHAT (OFF_QLN + 524288)
#define OFF_QXB  (OFF_QHAT + 524288)          // unused
#define OFF_P    (OFF_QXB + 524288)           // unused
#define OFF_M2   (OFF_P + 524288)
#define OFF_WQB  (OFF_M2 + 524288)            // unused
#define OFF_WCT  (OFF_WQB + 524288)           // WcT[512][512] bf16
#define OFF_KM   (OFF_WCT + 524288)           // 32768*4
#define OFF_KR   (OFF_KM + 131072)
#define OFF_T2   (OFF_KR + 131072)            // 512*4
#define OFF_FLAG (OFF_T2 + 4096)

// == PHASE 1 (512 thr): gram32 + prep_q + w2 cvt + h-GEMM + WcT + init + mask
__global__ __launch_bounds__(512) void k_phase1(
    const float* __restrict__ qx, const float* __restrict__ kx,
    const int* __restrict__ maskw,
    const float* __restrict__ g_q, const float* __restrict__ b_q,
    const float* __restrict__ wq, const float* __restrict__ wk,
    const float* __restrict__ w1, const float* __restrict__ b1,
    const float* __restrict__ w2, const float* __restrict__ b2,
    u16* __restrict__ kxb, float* __restrict__ km, float* __restrict__ kr,
    u16* __restrict__ Gm,
    u16* __restrict__ qln, u16* __restrict__ qhat,
    u16* __restrict__ wct, u16* __restrict__ w2b, u16* __restrict__ hbuf,
    float* __restrict__ t2s, int* __restrict__ flag, float* __restrict__ x1o)
{
  __shared__ __align__(16) u16 lBig[16384];   // 32KB overlay
  __shared__ float redq[8][2];
  __shared__ int smax;
  const int bid = blockIdx.x, tid = threadIdx.x;
  const int lane = tid & 63, w = tid >> 6;
  const int l15 = lane & 15, lg = lane >> 4;

  if (bid < 256){
    // ---------------- gram32 (proven) ----------------
    u16* lk = lBig;
    const int z = bid;
    const int a0 = (w>>2)*64, b0 = (w&3)*32;
    float s[16] = {0,0,0,0,0,0,0,0,0,0,0,0,0,0,0,0};
    float sq[16] = {0,0,0,0,0,0,0,0,0,0,0,0,0,0,0,0};
    f32x4 acc[4][2] = {};
    for (int ch = 0; ch < 4; ch++){
      #pragma unroll
      for (int i = 0; i < 16; i++){
        int r = w*16 + i;
        float2 v = *(const float2*)(kx + ((size_t)z*128 + r)*512 + ch*128 + lane*2);
        s[i] += v.x + v.y; sq[i] += v.x*v.x + v.y*v.y;
        u32 pk = f2bf(v.x) | ((u32)f2bf(v.y)<<16);
        *(u32*)(kxb + ((size_t)z*128 + r)*512 + ch*128 + lane*2) = pk;
        *(u32*)&lk[r*128 + ((lane*2) ^ ((r&7)<<3))] = pk;
      }
      __syncthreads();
      #pragma unroll
      for (int kk = 0; kk < 4; kk++){
        int cgr = kk*4 + lg;
        bf16x8s a[4], b[2];
        #pragma unroll
        for (int i2 = 0; i2 < 4; i2++){
          int r = a0 + i2*16 + l15;
          a[i2] = *(const bf16x8s*)&lk[r*128 + ((cgr*8) ^ ((r&7)<<3))];
        }
        #pragma unroll
        for (int j = 0; j < 2; j++){
          int r = b0 + j*16 + l15;
          b[j] = *(const bf16x8s*)&lk[r*128 + ((cgr*8) ^ ((r&7)<<3))];
        }
        #pragma unroll
        for (int i2 = 0; i2 < 4; i2++)
          #pragma unroll
          for (int j = 0; j < 2; j++)
            acc[i2][j] = MFMA16(a[i2], b[j], acc[i2][j], 0,0,0);
      }
      __syncthreads();
    }
    #pragma unroll
    for (int i = 0; i < 16; i++){
      float ss = s[i], qq = sq[i];
      #pragma unroll
      for (int o = 1; o < 64; o <<= 1){ ss += __shfl_xor(ss,o); qq += __shfl_xor(qq,o); }
      if (lane == 0){
        int r = w*16 + i;
        float mean = ss*(1.0f/512.0f);
        float var  = qq*(1.0f/512.0f) - mean*mean;
        km[z*128+r] = mean; kr[z*128+r] = rsqrtf(var + 1e-5f);
      }
    }
    u16* G = Gm + (size_t)z*16384;
    #pragma unroll
    for (int i2 = 0; i2 < 4; i2++)
      #pragma unroll
      for (int j = 0; j < 2; j++)
        #pragma unroll
        for (int r = 0; r < 4; r++)
          G[(size_t)(a0 + i2*16 + lg*4 + r)*128 + b0 + j*16 + l15] = f2bf(acc[i2][j][r]);
  } else if (bid < 512){
    // ---------------- prep_q: 2 rows/block (qln, qhat) ----------------
    const int row = (bid-256)*2 + (tid>>8);
    const int t = tid & 255;
    float2 v = *(const float2*)(qx + (size_t)row*512 + t*2);
    float s = v.x+v.y, sq = v.x*v.x+v.y*v.y;
    #pragma unroll
    for (int o = 1; o < 64; o <<= 1){ s += __shfl_xor(s,o); sq += __shfl_xor(sq,o); }
    if (lane == 0){ redq[w][0]=s; redq[w][1]=sq; }
    __syncthreads();
    const int h4 = (tid>>8)*4;
    s  = redq[h4][0]+redq[h4+1][0]+redq[h4+2][0]+redq[h4+3][0];
    sq = redq[h4][1]+redq[h4+1][1]+redq[h4+2][1]+redq[h4+3][1];
    float mean = s*(1.0f/512.0f);
    float var  = sq*(1.0f/512.0f) - mean*mean;
    float rstd = rsqrtf(var + 1e-5f);
    float il2  = 1.0f / fmaxf(sqrtf(sq), 1e-12f);
    float2 g  = *(const float2*)(g_q + t*2);
    float2 bb = *(const float2*)(b_q + t*2);
    u32 a  = f2bf((v.x-mean)*rstd*g.x+bb.x) | ((u32)f2bf((v.y-mean)*rstd*g.y+bb.y)<<16);
    u32 hh = f2bf(v.x*il2) | ((u32)f2bf(v.y*il2)<<16);
    *(u32*)(qln  + (size_t)row*512 + t*2) = a;
    *(u32*)(qhat + (size_t)row*512 + t*2) = hh;
  } else if (bid < 1512){
    int i = (bid-512)*512 + tid;
    float4 v = *(const float4*)(w2 + (size_t)i*4);
    uint2 p;
    p.x = f2bf(v.x)|((u32)f2bf(v.y)<<16); p.y = f2bf(v.z)|((u32)f2bf(v.w)<<16);
    *(uint2*)(w2b + (size_t)i*4) = p;
  } else if (bid < 1640){
    // ------ h = relu(qx@w1^T + b1): direct f32 reads, convert in regs ------
    const int t = bid - 1512;                 // 0..127
    const int m0 = (t >> 4)*64, n0 = (t & 15)*128;
    const int w4 = w & 3;
    const int nb = (w >> 2)*64;
    const int wr = (w4>>1)*32, wc = (w4&1)*32;
    u16* shA = lBig;                          // [64][64]
    u16* shB = lBig + 4096;                   // [128][64]
    f32x4 acc[2][2] = {};
    for (int kc = 0; kc < 512; kc += 64){
      {
        int row = tid >> 3, c8 = (tid & 7)*8;
        float4 a0 = *(const float4*)(qx + (size_t)(m0+row)*512 + kc + c8);
        float4 a1 = *(const float4*)(qx + (size_t)(m0+row)*512 + kc + c8 + 4);
        u16 ta[8] = {f2bf(a0.x),f2bf(a0.y),f2bf(a0.z),f2bf(a0.w),
                     f2bf(a1.x),f2bf(a1.y),f2bf(a1.z),f2bf(a1.w)};
        *(uint4*)&shA[row*64 + (((tid&7) ^ (row&7))*8)] = *(uint4*)ta;
        #pragma unroll
        for (int s2 = 0; s2 < 2; s2++){
          int u = tid + s2*512;
          int rowb = u >> 3, cb8 = (u & 7)*8;
          float4 b0 = *(const float4*)(w1 + (size_t)(n0+rowb)*512 + kc + cb8);
          float4 b1v = *(const float4*)(w1 + (size_t)(n0+rowb)*512 + kc + cb8 + 4);
          u16 tb[8] = {f2bf(b0.x),f2bf(b0.y),f2bf(b0.z),f2bf(b0.w),
                       f2bf(b1v.x),f2bf(b1v.y),f2bf(b1v.z),f2bf(b1v.w)};
          *(uint4*)&shB[rowb*64 + (((u&7) ^ (rowb&7))*8)] = *(uint4*)tb;
        }
      }
      __syncthreads();
      #pragma unroll
      for (int kk = 0; kk < 2; kk++){
        int cgr = kk*4 + lg;
        int ra0 = wr + l15, ra1 = wr + 16 + l15;
        int rb0 = nb + wc + l15, rb1 = nb + wc + 16 + l15;
        bf16x8s a0 = *(const bf16x8s*)&shA[ra0*64 + ((cgr ^ (ra0&7))*8)];
        bf16x8s a1 = *(const bf16x8s*)&shA[ra1*64 + ((cgr ^ (ra1&7))*8)];
        bf16x8s b0 = *(const bf16x8s*)&shB[rb0*64 + ((cgr ^ (rb0&7))*8)];
        bf16x8s b1 = *(const bf16x8s*)&shB[rb1*64 + ((cgr ^ (rb1&7))*8)];
        acc[0][0]=MFMA16(a0,b0,acc[0][0],0,0,0);
        acc[0][1]=MFMA16(a0,b1,acc[0][1],0,0,0);
        acc[1][0]=MFMA16(a1,b0,acc[1][0],0,0,0);
        acc[1][1]=MFMA16(a1,b1,acc[1][1],0,0,0);
      }
      __syncthreads();
    }
    #pragma unroll
    for (int i = 0; i < 2; i++)
      #pragma unroll
      for (int j = 0; j < 2; j++){
        int col = n0 + nb + wc + j*16 + l15;
        float bv = b1[col];
        #pragma unroll
        for (int r = 0; r < 4; r++){
          int row = m0 + wr + i*16 + lg*4 + r;
          hbuf[(size_t)row*2048 + col] = f2bf(fmaxf(acc[i][j][r] + bv, 0.0f));
        }
      }
  } else if (bid < 1704){
    // -------- WcT[f][c] = sum_i wk[i][f]*wq[i][c] (512thr, w>=4 dup) --------
    const int t = bid - 1640;
    const int f0 = (t>>3)*64, c0 = (t&7)*64;
    const int w4 = w & 3;
    const int wr = (w4>>1)*32, wc = (w4&1)*32;
    u16* shA = lBig;
    u16* shB = lBig + 4096;
    f32x4 acc[2][2] = {};
    for (int i0 = 0; i0 < 512; i0 += 64){
      const int ii = tid >> 3;
      const int cc8 = (tid & 7) * 8;
      float4 va0 = *(const float4*)(wk + (size_t)(i0+ii)*512 + f0 + cc8);
      float4 va1 = *(const float4*)(wk + (size_t)(i0+ii)*512 + f0 + cc8 + 4);
      float4 vb0 = *(const float4*)(wq + (size_t)(i0+ii)*512 + c0 + cc8);
      float4 vb1 = *(const float4*)(wq + (size_t)(i0+ii)*512 + c0 + cc8 + 4);
      #pragma unroll
      for (int e = 0; e < 8; e++){
        float fa = e < 4 ? (&va0.x)[e] : (&va1.x)[e-4];
        float fb = e < 4 ? (&vb0.x)[e] : (&vb1.x)[e-4];
        int rowc = cc8 + e;
        int idx = rowc*64 + (((ii>>3) ^ (rowc&7))*8 + (ii&7));
        shA[idx] = f2bf(fa);
        shB[idx] = f2bf(fb);
      }
      __syncthreads();
      #pragma unroll
      for (int kk = 0; kk < 2; kk++){
        int cgr = kk*4 + lg;
        int ra0 = wr + l15, ra1 = wr + 16 + l15;
        int rb0 = wc + l15, rb1 = wc + 16 + l15;
        bf16x8s a0 = *(const bf16x8s*)&shA[ra0*64 + ((cgr ^ (ra0&7))*8)];
        bf16x8s a1 = *(const bf16x8s*)&shA[ra1*64 + ((cgr ^ (ra1&7))*8)];
        bf16x8s b0 = *(const bf16x8s*)&shB[rb0*64 + ((cgr ^ (rb0&7))*8)];
        bf16x8s b1 = *(const bf16x8s*)&shB[rb1*64 + ((cgr ^ (rb1&7))*8)];
        acc[0][0]=MFMA16(a0,b0,acc[0][0],0,0,0);
        acc[0][1]=MFMA16(a0,b1,acc[0][1],0,0,0);
        acc[1][0]=MFMA16(a1,b0,acc[1][0],0,0,0);
        acc[1][1]=MFMA16(a1,b1,acc[1][1],0,0,0);
      }
      __syncthreads();
    }
    if (tid < 256){
      #pragma unroll
      for (int i = 0; i < 2; i++)
        #pragma unroll
        for (int j = 0; j < 2; j++)
          #pragma unroll
          for (int r = 0; r < 4; r++)
            wct[(size_t)(f0 + wr + i*16 + lg*4 + r)*512 + c0 + wc + j*16 + l15]
                = f2bf(acc[i][j][r]);
    }
  } else if (bid < 1954){
    // -------- x1o bias-init --------
    int i = (bid-1704)*2048 + tid*4;
    #pragma unroll
    for (int e = 0; e < 4; e++){
      int idx = i + e;
      x1o[idx] = b2[idx % 1000];
    }
  } else {
    if (tid == 0) smax = 0;
    t2s[tid] = 0.0f;
    __syncthreads();
    int mx = 0;
    for (int i = tid; i < 8192; i += 512){ int v = maskw[i]; mx = v > mx ? v : mx; }
    #pragma unroll
    for (int o = 1; o < 64; o <<= 1){ int t2 = __shfl_xor(mx,o); mx = t2 > mx ? t2 : mx; }
    if ((tid & 63) == 0) atomicMax(&smax, mx);
    __syncthreads();
    if (tid == 0) *flag = (smax <= 1) ? 1 : 0;
  }
}

// ------------- 64x64 GEMM body (proven, register-staged) ---------
__device__ __forceinline__ void gemm_body(const u16* __restrict__ Ap, const u16* __restrict__ Bp,
    int M, int N, int K, int m0, int n0, int tid,
    u16 (*lA)[64], u16 (*lB)[64], f32x4 (&acc)[2][2])
{
  const int lane = tid & 63, w = tid >> 6;
  const int wr = (w >> 1)*32, wc = (w & 1)*32;
  const int l15 = lane & 15, lg = lane >> 4;
  for (int kc = 0; kc < K; kc += 64){
    #pragma unroll
    for (int s = 0; s < 2; s++){
      int u = tid + s*256;
      int row = u >> 3, cg = u & 7;
      int sw = (cg ^ (row & 7)) * 8;
      uint4 va = make_uint4(0,0,0,0);
      if (m0 + row < M) va = *(const uint4*)(Ap + (size_t)(m0+row)*K + kc + cg*8);
      *(uint4*)&lA[row][sw] = va;
      uint4 vb = make_uint4(0,0,0,0);
      if (n0 + row < N) vb = *(const uint4*)(Bp + (size_t)(n0+row)*K + kc + cg*8);
      *(uint4*)&lB[row][sw] = vb;
    }
    __syncthreads();
    #pragma unroll
    for (int kk = 0; kk < 2; kk++){
      int cgr = kk*4 + lg;
      int ra0 = wr + l15, ra1 = wr + 16 + l15;
      int rb0 = wc + l15, rb1 = wc + 16 + l15;
      bf16x8s a0 = *(const bf16x8s*)&lA[ra0][(cgr ^ (ra0&7))*8];
      bf16x8s a1 = *(const bf16x8s*)&lA[ra1][(cgr ^ (ra1&7))*8];
      bf16x8s b0 = *(const bf16x8s*)&lB[rb0][(cgr ^ (rb0&7))*8];
      bf16x8s b1 = *(const bf16x8s*)&lB[rb1][(cgr ^ (rb1&7))*8];
      acc[0][0] = MFMA16(a0,b0,acc[0][0],0,0,0);
      acc[0][1] = MFMA16(a0,b1,acc[0][1],0,0,0);
      acc[1][0] = MFMA16(a1,b0,acc[1][0],0,0,0);
      acc[1][1] = MFMA16(a1,b1,acc[1][1],0,0,0);
    }
    __syncthreads();
  }
}

// ===== PHASE 2: x1 K-split (atomicAdd) first, then pw = qln@WcT (+m2/t2) ===
__global__ __launch_bounds__(256) void k_phase2(
    const u16* __restrict__ qln, const u16* __restrict__ wct,
    const float* __restrict__ g_k, u16* __restrict__ m2, float* __restrict__ t2s,
    const u16* __restrict__ hbuf, const u16* __restrict__ w2b,
    float* __restrict__ x1o)
{
  __shared__ __align__(16) u16 lA[64][64], lB[64][64];
  f32x4 acc[2][2] = {};
  const int bid = blockIdx.x, tid = threadIdx.x;
  const int lane = tid & 63, w = tid >> 6;
  const int wr = (w >> 1)*32, wc = (w & 1)*32;
  const int l15 = lane & 15, lg = lane >> 4;
  if (bid < 512){
    const int ks = bid >> 7;
    const int t  = bid & 127;
    const int m0 = (t >> 4)*64, n0 = (t & 15)*64;
    for (int kc = ks*512; kc < ks*512 + 512; kc += 64){
      #pragma unroll
      for (int s = 0; s < 2; s++){
        int u = tid + s*256;
        int row = u >> 3, cg = u & 7;
        int sw = (cg ^ (row & 7)) * 8;
        *(uint4*)&lA[row][sw] = *(const uint4*)(hbuf + (size_t)(m0+row)*2048 + kc + cg*8);
        uint4 vb = make_uint4(0,0,0,0);
        if (n0 + row < 1000) vb = *(const uint4*)(w2b + (size_t)(n0+row)*2048 + kc + cg*8);
        *(uint4*)&lB[row][sw] = vb;
      }
      __syncthreads();
      #pragma unroll
      for (int kk = 0; kk < 2; kk++){
        int cgr = kk*4 + lg;
        int ra0 = wr + l15, ra1 = wr + 16 + l15;
        int rb0 = wc + l15, rb1 = wc + 16 + l15;
        bf16x8s a0 = *(const bf16x8s*)&lA[ra0][(cgr ^ (ra0&7))*8];
        bf16x8s a1 = *(const bf16x8s*)&lA[ra1][(cgr ^ (ra1&7))*8];
        bf16x8s b0 = *(const bf16x8s*)&lB[rb0][(cgr ^ (rb0&7))*8];
        bf16x8s b1 = *(const bf16x8s*)&lB[rb1][(cgr ^ (rb1&7))*8];
        acc[0][0]=MFMA16(a0,b0,acc[0][0],0,0,0);
        acc[0][1]=MFMA16(a0,b1,acc[0][1],0,0,0);
        acc[1][0]=MFMA16(a1,b0,acc[1][0],0,0,0);
        acc[1][1]=MFMA16(a1,b1,acc[1][1],0,0,0);
      }
      __syncthreads();
    }
    #pragma unroll
    for (int i = 0; i < 2; i++)
      #pragma unroll
      for (int j = 0; j < 2; j++){
        int col = n0 + wc + j*16 + l15;
        if (col < 1000){
          #pragma unroll
          for (int r = 0; r < 4; r++){
            int row = m0 + wr + i*16 + lg*4 + r;
            atomicAdd(&x1o[(size_t)row*1000 + col], acc[i][j][r]);
          }
        }
      }
  } else {
    const int b = bid - 512;
    int m0 = (b>>3)*64, n0 = (b&7)*64;
    gemm_body(qln, wct, 512,512,512, m0,n0, tid, lA, lB, acc);
    #pragma unroll
    for (int i = 0; i < 2; i++){
      #pragma unroll
      for (int r = 0; r < 4; r++){
        int row = m0 + wr + i*16 + lg*4 + r;
        float part = 0.f;
        #pragma unroll
        for (int j = 0; j < 2; j++){
          int col = n0 + wc + j*16 + l15;
          float e = SCALE_C * acc[i][j][r] * g_k[col];
          m2[(size_t)row*512 + col] = f2bf(e);
          part += e;
        }
        #pragma unroll
        for (int o = 1; o < 16; o <<= 1) part += __shfl_xor(part, o);
        if (l15 == 0) atomicAdd(&t2s[row], part);
      }
    }
  }
}

// == PHASE 3: attn q-tile 64: 16-phase counted-vmcnt, conflict-free swizzle,
//    XCD-chunked. LDS ~35KB -> 4 blocks/CU (was 3 + tail round at 51.7KB).
//    grid 2048 = exactly 2 full dispatch rounds.
__global__ __launch_bounds__(512, 8) void k_attn(
    const u16* __restrict__ kxb, const u16* __restrict__ Gm,
    const u16* __restrict__ m2, const u16* __restrict__ qhat,
    const float* __restrict__ km, const float* __restrict__ kr,
    const float* __restrict__ t2s, const void* __restrict__ maskp,
    const int* __restrict__ flagp, const float* __restrict__ lsp,
    float* __restrict__ x2)
{
  __shared__ __align__(16) u16 sb[16384];    // 32KB: 2 x {KX[128][32]|M2[64][32]|QH[64][32]}
  __shared__ float lt2[64];
  __shared__ float lNum[64][4], lDen[64][4];
  u16* lP = sb;                               // [64][128] = 8192 u16, aliases buf0

  const int bid = blockIdx.x;
  const int kb = (bid & 7)*32 + ((bid >> 3) & 31);   // XCD-chunked (bijective)
  const int q0 = (bid >> 8) * 64;                    // qt 0..7
  const int tid = threadIdx.x, lane = tid & 63, w = tid >> 6;
  const int wr = (w >> 2)*32;                 // q-row group (2)
  const int wcol = (w & 3)*32;                // kv-col group (4)
  const int cg4 = w & 3;
  const int l15 = lane & 15, lg = lane >> 4;

  const u16* KX = kxb + (size_t)kb * 65536;
  // KX staging: wave w -> rows [w*16, w*16+16)
  const int srow  = w*16 + (lane >> 2);
  const int sslot = (lane & 3) ^ ((srow >> 1) & 3);
  // M2 (waves 0-3) / QH (waves 4-7) staging: rows [(w&3)*16, +16) of q-tile
  const int qrow  = (w & 3)*16 + (lane >> 2);
  const int qslot = (lane & 3) ^ ((qrow >> 1) & 3);
  const u16* QS   = (w < 4) ? m2 : qhat;
  const int  qdst = 4096 + (w < 4 ? 0 : 2048) + (w & 3)*512;   // u16 offset in buf

  #define STAGE(p) do{                                                         \
    const int kc_ = (p)*32;                                                    \
    u16* b_ = sb + ((p)&1)*8192;                                               \
    gload16(KX + (size_t)srow*512      + kc_ + sslot*8, b_ + w*512);            \
    gload16(QS + (size_t)(q0+qrow)*512 + kc_ + qslot*8, b_ + qdst);             \
  }while(0)

  STAGE(0);

  const int fl = *flagp;
  const float expls = __expf(lsp[0]);
  if (tid < 64) lt2[tid] = t2s[q0 + tid];

  float kmv[2], krv[2], mbv[2];
  #pragma unroll
  for (int j = 0; j < 2; j++){
    int gn = kb*128 + wcol + j*16 + l15;
    kmv[j] = km[gn]; krv[j] = kr[gn];
    int mv = fl ? ((const int*)maskp)[gn] : (int)((const unsigned char*)maskp)[gn];
    mbv[j] = mv ? -1e30f : 0.0f;
  }

  f32x4 aS[2][2] = {}, aD[2][2] = {};

  #pragma unroll
  for (int p = 0; p < 16; p++){
    if (p < 15){
      STAGE(p+1);
      asm volatile("s_waitcnt vmcnt(2)" ::: "memory");
    } else {
      asm volatile("s_waitcnt vmcnt(0)" ::: "memory");
    }
    __builtin_amdgcn_s_barrier();
    __builtin_amdgcn_sched_barrier(0);
    const u16* lb  = sb + (p&1)*8192;
    const u16* lKX = lb;                       // [128][32]
    const u16* lM2 = lb + 4096;                // [64][32]
    const u16* lQH = lb + 6144;                // [64][32]
    const int rA0 = wr + l15, rA1 = wr + 16 + l15;
    bf16x8s am0 = *(const bf16x8s*)&lM2[rA0*32 + ((lg ^ ((rA0>>1)&3))*8)];
    bf16x8s am1 = *(const bf16x8s*)&lM2[rA1*32 + ((lg ^ ((rA1>>1)&3))*8)];
    bf16x8s aq0 = *(const bf16x8s*)&lQH[rA0*32 + ((lg ^ ((rA0>>1)&3))*8)];
    bf16x8s aq1 = *(const bf16x8s*)&lQH[rA1*32 + ((lg ^ ((rA1>>1)&3))*8)];
    __builtin_amdgcn_s_setprio(1);
    #pragma unroll
    for (int j = 0; j < 2; j++){
      int rB = wcol + j*16 + l15;              // kv 0..127
      bf16x8s bk = *(const bf16x8s*)&lKX[rB*32 + ((lg ^ ((rB>>1)&3))*8)];
      aS[0][j] = MFMA16(am0, bk, aS[0][j], 0,0,0);
      aS[1][j] = MFMA16(am1, bk, aS[1][j], 0,0,0);
      aD[0][j] = MFMA16(aq0, bk, aD[0][j], 0,0,0);
      aD[1][j] = MFMA16(aq1, bk, aD[1][j], 0,0,0);
    }
    __builtin_amdgcn_s_setprio(0);
    __builtin_amdgcn_sched_barrier(0);
    __builtin_amdgcn_s_barrier();
  }
  __syncthreads();   // full drain before P aliases sb

  // softmax (Z cancels in x2: raw E=exp(L)) + numer partials + P write
  #pragma unroll
  for (int i = 0; i < 2; i++){
    #pragma unroll
    for (int r = 0; r < 4; r++){
      int rowl = wr + i*16 + lg*4 + r;         // 0..63
      float t2v = lt2[rowl];
      float sn = 0.f;
      #pragma unroll
      for (int j = 0; j < 2; j++){
        float L = krv[j]*(aS[i][j][r] - kmv[j]*t2v) + mbv[j];
        float e = __expf(L);
        aS[i][j][r] = e;
        sn += e * aD[i][j][r];
      }
      #pragma unroll
      for (int o = 1; o < 16; o <<= 1) sn += __shfl_xor(sn, o);
      if (l15 == 0) lNum[rowl][cg4] = sn;
      #pragma unroll
      for (int j = 0; j < 2; j++){
        int n = wcol + j*16 + l15;              // 0..127
        lP[rowl*128 + ((n>>3)^(rowl&7))*8 + (n&7)] = f2bf(aS[i][j][r]);
      }
    }
  }
  __syncthreads();

  // T = E @ G (G symmetric: row-major B-frags straight from global, L2-hot)
  f32x4 aT[2][2] = {};
  const u16* Gk = Gm + (size_t)kb * 16384;
  #pragma unroll
  for (int kk = 0; kk < 4; kk++){
    int cgr = kk*4 + lg;
    int rA0 = wr + l15, rA1 = wr + 16 + l15;
    bf16x8s p0 = *(const bf16x8s*)&lP[rA0*128 + ((cgr^(rA0&7))*8)];
    bf16x8s p1 = *(const bf16x8s*)&lP[rA1*128 + ((cgr^(rA1&7))*8)];
    #pragma unroll
    for (int j = 0; j < 2; j++){
      int mcol = wcol + j*16 + l15;
      bf16x8s bg = *(const bf16x8s*)(Gk + (size_t)mcol*128 + kk*32 + lg*8);
      aT[0][j] = MFMA16(p0, bg, aT[0][j], 0,0,0);
      aT[1][j] = MFMA16(p1, bg, aT[1][j], 0,0,0);
    }
  }
  // denom^2 partials
  #pragma unroll
  for (int i = 0; i < 2; i++){
    #pragma unroll
    for (int r = 0; r < 4; r++){
      int rowl = wr + i*16 + lg*4 + r;
      float sd = 0.f;
      #pragma unroll
      for (int j = 0; j < 2; j++) sd += aT[i][j][r] * aS[i][j][r];
      #pragma unroll
      for (int o = 1; o < 16; o <<= 1) sd += __shfl_xor(sd, o);
      if (l15 == 0) lDen[rowl][cg4] = sd;
    }
  }
  __syncthreads();

  if (tid < 64){
    float num  = lNum[tid][0] + lNum[tid][1] + lNum[tid][2] + lNum[tid][3];
    float den2 = lDen[tid][0] + lDen[tid][1] + lDen[tid][2] + lDen[tid][3];
    float den  = fmaxf(sqrtf(fmaxf(den2, 0.0f)), 1e-12f);
    x2[(size_t)(q0 + tid)*256 + kb] = expls * num / den;
  }
}

// ---------------------------------------------------------------------------
extern "C" void kernel_launch(void* const* d_in, const int* in_sizes, int n_in,
                              void* d_out, int out_size, void* d_ws, size_t ws_size,
                              hipStream_t stream)
{
  (void)in_sizes; (void)n_in; (void)out_size; (void)ws_size;
  const float* qx  = (const float*)d_in[0];
  const float* kx  = (const float*)d_in[1];
  const void*  mask= d_in[2];
  const float* lsp = (const float*)d_in[3];
  const float* g_q = (const float*)d_in[4];
  const float* b_q = (const float*)d_in[5];
  const float* g_k = (const float*)d_in[6];
  // d_in[7] (b_k): softmax-invariant per-q constant, dropped
  const float* wq  = (const float*)d_in[8];
  const float* wk  = (const float*)d_in[9];
  const float* w1  = (const float*)d_in[10];
  const float* b1  = (const float*)d_in[11];
  const float* w2  = (const float*)d_in[12];
  const float* b2  = (const float*)d_in[13];

  char* ws = (char*)d_ws;
  u16* kxb  = (u16*)(ws + OFF_KXB);
  u16* Gm   = (u16*)(ws + OFF_G);
  u16* w2b  = (u16*)(ws + OFF_W2B);
  u16* hbuf = (u16*)(ws + OFF_H);
  u16* qln  = (u16*)(ws + OFF_QLN);
  u16* qhat = (u16*)(ws + OFF_QHAT);
  u16* m2   = (u16*)(ws + OFF_M2);
  u16* wct  = (u16*)(ws + OFF_WCT);
  float* km  = (float*)(ws + OFF_KM);
  float* kr  = (float*)(ws + OFF_KR);
  float* t2s = (float*)(ws + OFF_T2);
  int*   flag= (int*)(ws + OFF_FLAG);
  float* x1o = (float*)d_out;
  float* x2o = (float*)d_out + 512*1000;

  k_phase1<<<dim3(1955), dim3(512), 0, stream>>>(
      qx, kx, (const int*)mask, g_q, b_q, wq, wk, w1, b1, w2, b2,
      kxb, km, kr, Gm, qln, qhat, wct, w2b, hbuf, t2s, flag, x1o);
  k_phase2<<<dim3(576), dim3(256), 0, stream>>>(
      qln, wct, g_k, m2, t2s, hbuf, w2b, x1o);
  k_attn<<<dim3(2048), dim3(512), 0, stream>>>(
      kxb, Gm, m2, qhat, km, kr, t2s, mask, flag, lsp, x2o);
}

// Round 18
// 119.375 us; speedup vs baseline: 1.1271x; 1.1271x over previous
//
#include <hip/hip_runtime.h>

typedef unsigned short u16;
typedef unsigned int u32;
typedef short bf16x8s __attribute__((ext_vector_type(8)));
typedef float f32x4 __attribute__((ext_vector_type(4)));

#define SCALE_C 0.044194173824159216f  // 512^-0.5
#define MFMA16 __builtin_amdgcn_mfma_f32_16x16x32_bf16

__device__ __forceinline__ u16 f2bf(float f){
  union { float f; u32 u; } c; c.f = f;
  u32 u = c.u;
  return (u16)((u + 0x7fffu + ((u >> 16) & 1u)) >> 16);
}

__device__ __forceinline__ void gload16(const void* g, void* l){
  __builtin_amdgcn_global_load_lds((const __attribute__((address_space(1))) void*)g,
                                   (__attribute__((address_space(3))) void*)l, 16, 0, 0);
}

// ---------------- workspace layout (bytes) ----------------
#define OFF_KXB  ((size_t)0)                  // 32768*512*2
#define OFF_G    (OFF_KXB + 33554432)         // 256*128*128*2
#define OFF_W2B  (OFF_G + 8388608)            // 1000*2048*2
#define OFF_H    (OFF_W2B + 4096000)          // 512*2048*2
#define OFF_W1B  (OFF_H + 2097152)            // unused
#define OFF_QLN  (OFF_W1B + 2097152)
#define OFF_QHAT (OFF_QLN + 524288)
#define OFF_QXB  (OFF_QHAT + 524288)          // unused
#define OFF_P    (OFF_QXB + 524288)           // unused
#define OFF_M2   (OFF_P + 524288)
#define OFF_WQB  (OFF_M2 + 524288)            // unused
#define OFF_WCT  (OFF_WQB + 524288)           // WcT[512][512] bf16
#define OFF_KM   (OFF_WCT + 524288)           // 32768*4
#define OFF_KR   (OFF_KM + 131072)
#define OFF_T2   (OFF_KR + 131072)            // 512*4
#define OFF_FLAG (OFF_T2 + 4096)

// == PHASE 1 (512 thr): gram32 + prep_q + w2 cvt + h-GEMM + WcT + init + mask
__global__ __launch_bounds__(512) void k_phase1(
    const float* __restrict__ qx, const float* __restrict__ kx,
    const int* __restrict__ maskw,
    const float* __restrict__ g_q, const float* __restrict__ b_q,
    const float* __restrict__ wq, const float* __restrict__ wk,
    const float* __restrict__ w1, const float* __restrict__ b1,
    const float* __restrict__ w2, const float* __restrict__ b2,
    u16* __restrict__ kxb, float* __restrict__ km, float* __restrict__ kr,
    u16* __restrict__ Gm,
    u16* __restrict__ qln, u16* __restrict__ qhat,
    u16* __restrict__ wct, u16* __restrict__ w2b, u16* __restrict__ hbuf,
    float* __restrict__ t2s, int* __restrict__ flag, float* __restrict__ x1o)
{
  __shared__ __align__(16) u16 lBig[16384];   // 32KB overlay
  __shared__ float redq[8][2];
  __shared__ int smax;
  const int bid = blockIdx.x, tid = threadIdx.x;
  const int lane = tid & 63, w = tid >> 6;
  const int l15 = lane & 15, lg = lane >> 4;

  if (bid < 256){
    // ---------------- gram32 (proven) ----------------
    u16* lk = lBig;
    const int z = bid;
    const int a0 = (w>>2)*64, b0 = (w&3)*32;
    float s[16] = {0,0,0,0,0,0,0,0,0,0,0,0,0,0,0,0};
    float sq[16] = {0,0,0,0,0,0,0,0,0,0,0,0,0,0,0,0};
    f32x4 acc[4][2] = {};
    for (int ch = 0; ch < 4; ch++){
      #pragma unroll
      for (int i = 0; i < 16; i++){
        int r = w*16 + i;
        float2 v = *(const float2*)(kx + ((size_t)z*128 + r)*512 + ch*128 + lane*2);
        s[i] += v.x + v.y; sq[i] += v.x*v.x + v.y*v.y;
        u32 pk = f2bf(v.x) | ((u32)f2bf(v.y)<<16);
        *(u32*)(kxb + ((size_t)z*128 + r)*512 + ch*128 + lane*2) = pk;
        *(u32*)&lk[r*128 + ((lane*2) ^ ((r&7)<<3))] = pk;
      }
      __syncthreads();
      #pragma unroll
      for (int kk = 0; kk < 4; kk++){
        int cgr = kk*4 + lg;
        bf16x8s a[4], b[2];
        #pragma unroll
        for (int i2 = 0; i2 < 4; i2++){
          int r = a0 + i2*16 + l15;
          a[i2] = *(const bf16x8s*)&lk[r*128 + ((cgr*8) ^ ((r&7)<<3))];
        }
        #pragma unroll
        for (int j = 0; j < 2; j++){
          int r = b0 + j*16 + l15;
          b[j] = *(const bf16x8s*)&lk[r*128 + ((cgr*8) ^ ((r&7)<<3))];
        }
        #pragma unroll
        for (int i2 = 0; i2 < 4; i2++)
          #pragma unroll
          for (int j = 0; j < 2; j++)
            acc[i2][j] = MFMA16(a[i2], b[j], acc[i2][j], 0,0,0);
      }
      __syncthreads();
    }
    #pragma unroll
    for (int i = 0; i < 16; i++){
      float ss = s[i], qq = sq[i];
      #pragma unroll
      for (int o = 1; o < 64; o <<= 1){ ss += __shfl_xor(ss,o); qq += __shfl_xor(qq,o); }
      if (lane == 0){
        int r = w*16 + i;
        float mean = ss*(1.0f/512.0f);
        float var  = qq*(1.0f/512.0f) - mean*mean;
        km[z*128+r] = mean; kr[z*128+r] = rsqrtf(var + 1e-5f);
      }
    }
    u16* G = Gm + (size_t)z*16384;
    #pragma unroll
    for (int i2 = 0; i2 < 4; i2++)
      #pragma unroll
      for (int j = 0; j < 2; j++)
        #pragma unroll
        for (int r = 0; r < 4; r++)
          G[(size_t)(a0 + i2*16 + lg*4 + r)*128 + b0 + j*16 + l15] = f2bf(acc[i2][j][r]);
  } else if (bid < 512){
    // ---------------- prep_q: 2 rows/block (qln, qhat) ----------------
    const int row = (bid-256)*2 + (tid>>8);
    const int t = tid & 255;
    float2 v = *(const float2*)(qx + (size_t)row*512 + t*2);
    float s = v.x+v.y, sq = v.x*v.x+v.y*v.y;
    #pragma unroll
    for (int o = 1; o < 64; o <<= 1){ s += __shfl_xor(s,o); sq += __shfl_xor(sq,o); }
    if (lane == 0){ redq[w][0]=s; redq[w][1]=sq; }
    __syncthreads();
    const int h4 = (tid>>8)*4;
    s  = redq[h4][0]+redq[h4+1][0]+redq[h4+2][0]+redq[h4+3][0];
    sq = redq[h4][1]+redq[h4+1][1]+redq[h4+2][1]+redq[h4+3][1];
    float mean = s*(1.0f/512.0f);
    float var  = sq*(1.0f/512.0f) - mean*mean;
    float rstd = rsqrtf(var + 1e-5f);
    float il2  = 1.0f / fmaxf(sqrtf(sq), 1e-12f);
    float2 g  = *(const float2*)(g_q + t*2);
    float2 bb = *(const float2*)(b_q + t*2);
    u32 a  = f2bf((v.x-mean)*rstd*g.x+bb.x) | ((u32)f2bf((v.y-mean)*rstd*g.y+bb.y)<<16);
    u32 hh = f2bf(v.x*il2) | ((u32)f2bf(v.y*il2)<<16);
    *(u32*)(qln  + (size_t)row*512 + t*2) = a;
    *(u32*)(qhat + (size_t)row*512 + t*2) = hh;
  } else if (bid < 1512){
    int i = (bid-512)*512 + tid;
    float4 v = *(const float4*)(w2 + (size_t)i*4);
    uint2 p;
    p.x = f2bf(v.x)|((u32)f2bf(v.y)<<16); p.y = f2bf(v.z)|((u32)f2bf(v.w)<<16);
    *(uint2*)(w2b + (size_t)i*4) = p;
  } else if (bid < 1640){
    // ------ h = relu(qx@w1^T + b1): direct f32 reads, convert in regs ------
    const int t = bid - 1512;                 // 0..127
    const int m0 = (t >> 4)*64, n0 = (t & 15)*128;
    const int w4 = w & 3;
    const int nb = (w >> 2)*64;
    const int wr = (w4>>1)*32, wc = (w4&1)*32;
    u16* shA = lBig;                          // [64][64]
    u16* shB = lBig + 4096;                   // [128][64]
    f32x4 acc[2][2] = {};
    for (int kc = 0; kc < 512; kc += 64){
      {
        int row = tid >> 3, c8 = (tid & 7)*8;
        float4 a0 = *(const float4*)(qx + (size_t)(m0+row)*512 + kc + c8);
        float4 a1 = *(const float4*)(qx + (size_t)(m0+row)*512 + kc + c8 + 4);
        u16 ta[8] = {f2bf(a0.x),f2bf(a0.y),f2bf(a0.z),f2bf(a0.w),
                     f2bf(a1.x),f2bf(a1.y),f2bf(a1.z),f2bf(a1.w)};
        *(uint4*)&shA[row*64 + (((tid&7) ^ (row&7))*8)] = *(uint4*)ta;
        #pragma unroll
        for (int s2 = 0; s2 < 2; s2++){
          int u = tid + s2*512;
          int rowb = u >> 3, cb8 = (u & 7)*8;
          float4 b0 = *(const float4*)(w1 + (size_t)(n0+rowb)*512 + kc + cb8);
          float4 b1v = *(const float4*)(w1 + (size_t)(n0+rowb)*512 + kc + cb8 + 4);
          u16 tb[8] = {f2bf(b0.x),f2bf(b0.y),f2bf(b0.z),f2bf(b0.w),
                       f2bf(b1v.x),f2bf(b1v.y),f2bf(b1v.z),f2bf(b1v.w)};
          *(uint4*)&shB[rowb*64 + (((u&7) ^ (rowb&7))*8)] = *(uint4*)tb;
        }
      }
      __syncthreads();
      #pragma unroll
      for (int kk = 0; kk < 2; kk++){
        int cgr = kk*4 + lg;
        int ra0 = wr + l15, ra1 = wr + 16 + l15;
        int rb0 = nb + wc + l15, rb1 = nb + wc + 16 + l15;
        bf16x8s a0 = *(const bf16x8s*)&shA[ra0*64 + ((cgr ^ (ra0&7))*8)];
        bf16x8s a1 = *(const bf16x8s*)&shA[ra1*64 + ((cgr ^ (ra1&7))*8)];
        bf16x8s b0 = *(const bf16x8s*)&shB[rb0*64 + ((cgr ^ (rb0&7))*8)];
        bf16x8s b1 = *(const bf16x8s*)&shB[rb1*64 + ((cgr ^ (rb1&7))*8)];
        acc[0][0]=MFMA16(a0,b0,acc[0][0],0,0,0);
        acc[0][1]=MFMA16(a0,b1,acc[0][1],0,0,0);
        acc[1][0]=MFMA16(a1,b0,acc[1][0],0,0,0);
        acc[1][1]=MFMA16(a1,b1,acc[1][1],0,0,0);
      }
      __syncthreads();
    }
    #pragma unroll
    for (int i = 0; i < 2; i++)
      #pragma unroll
      for (int j = 0; j < 2; j++){
        int col = n0 + nb + wc + j*16 + l15;
        float bv = b1[col];
        #pragma unroll
        for (int r = 0; r < 4; r++){
          int row = m0 + wr + i*16 + lg*4 + r;
          hbuf[(size_t)row*2048 + col] = f2bf(fmaxf(acc[i][j][r] + bv, 0.0f));
        }
      }
  } else if (bid < 1704){
    // -------- WcT[f][c] = sum_i wk[i][f]*wq[i][c] (512thr, w>=4 dup) --------
    const int t = bid - 1640;
    const int f0 = (t>>3)*64, c0 = (t&7)*64;
    const int w4 = w & 3;
    const int wr = (w4>>1)*32, wc = (w4&1)*32;
    u16* shA = lBig;
    u16* shB = lBig + 4096;
    f32x4 acc[2][2] = {};
    for (int i0 = 0; i0 < 512; i0 += 64){
      const int ii = tid >> 3;
      const int cc8 = (tid & 7) * 8;
      float4 va0 = *(const float4*)(wk + (size_t)(i0+ii)*512 + f0 + cc8);
      float4 va1 = *(const float4*)(wk + (size_t)(i0+ii)*512 + f0 + cc8 + 4);
      float4 vb0 = *(const float4*)(wq + (size_t)(i0+ii)*512 + c0 + cc8);
      float4 vb1 = *(const float4*)(wq + (size_t)(i0+ii)*512 + c0 + cc8 + 4);
      #pragma unroll
      for (int e = 0; e < 8; e++){
        float fa = e < 4 ? (&va0.x)[e] : (&va1.x)[e-4];
        float fb = e < 4 ? (&vb0.x)[e] : (&vb1.x)[e-4];
        int rowc = cc8 + e;
        int idx = rowc*64 + (((ii>>3) ^ (rowc&7))*8 + (ii&7));
        shA[idx] = f2bf(fa);
        shB[idx] = f2bf(fb);
      }
      __syncthreads();
      #pragma unroll
      for (int kk = 0; kk < 2; kk++){
        int cgr = kk*4 + lg;
        int ra0 = wr + l15, ra1 = wr + 16 + l15;
        int rb0 = wc + l15, rb1 = wc + 16 + l15;
        bf16x8s a0 = *(const bf16x8s*)&shA[ra0*64 + ((cgr ^ (ra0&7))*8)];
        bf16x8s a1 = *(const bf16x8s*)&shA[ra1*64 + ((cgr ^ (ra1&7))*8)];
        bf16x8s b0 = *(const bf16x8s*)&shB[rb0*64 + ((cgr ^ (rb0&7))*8)];
        bf16x8s b1 = *(const bf16x8s*)&shB[rb1*64 + ((cgr ^ (rb1&7))*8)];
        acc[0][0]=MFMA16(a0,b0,acc[0][0],0,0,0);
        acc[0][1]=MFMA16(a0,b1,acc[0][1],0,0,0);
        acc[1][0]=MFMA16(a1,b0,acc[1][0],0,0,0);
        acc[1][1]=MFMA16(a1,b1,acc[1][1],0,0,0);
      }
      __syncthreads();
    }
    if (tid < 256){
      #pragma unroll
      for (int i = 0; i < 2; i++)
        #pragma unroll
        for (int j = 0; j < 2; j++)
          #pragma unroll
          for (int r = 0; r < 4; r++)
            wct[(size_t)(f0 + wr + i*16 + lg*4 + r)*512 + c0 + wc + j*16 + l15]
                = f2bf(acc[i][j][r]);
    }
  } else if (bid < 1954){
    // -------- x1o bias-init --------
    int i = (bid-1704)*2048 + tid*4;
    #pragma unroll
    for (int e = 0; e < 4; e++){
      int idx = i + e;
      x1o[idx] = b2[idx % 1000];
    }
  } else {
    if (tid == 0) smax = 0;
    t2s[tid] = 0.0f;
    __syncthreads();
    int mx = 0;
    for (int i = tid; i < 8192; i += 512){ int v = maskw[i]; mx = v > mx ? v : mx; }
    #pragma unroll
    for (int o = 1; o < 64; o <<= 1){ int t2 = __shfl_xor(mx,o); mx = t2 > mx ? t2 : mx; }
    if ((tid & 63) == 0) atomicMax(&smax, mx);
    __syncthreads();
    if (tid == 0) *flag = (smax <= 1) ? 1 : 0;
  }
}

// ------------- 64x64 GEMM body (proven, register-staged) ---------
__device__ __forceinline__ void gemm_body(const u16* __restrict__ Ap, const u16* __restrict__ Bp,
    int M, int N, int K, int m0, int n0, int tid,
    u16 (*lA)[64], u16 (*lB)[64], f32x4 (&acc)[2][2])
{
  const int lane = tid & 63, w = tid >> 6;
  const int wr = (w >> 1)*32, wc = (w & 1)*32;
  const int l15 = lane & 15, lg = lane >> 4;
  for (int kc = 0; kc < K; kc += 64){
    #pragma unroll
    for (int s = 0; s < 2; s++){
      int u = tid + s*256;
      int row = u >> 3, cg = u & 7;
      int sw = (cg ^ (row & 7)) * 8;
      uint4 va = make_uint4(0,0,0,0);
      if (m0 + row < M) va = *(const uint4*)(Ap + (size_t)(m0+row)*K + kc + cg*8);
      *(uint4*)&lA[row][sw] = va;
      uint4 vb = make_uint4(0,0,0,0);
      if (n0 + row < N) vb = *(const uint4*)(Bp + (size_t)(n0+row)*K + kc + cg*8);
      *(uint4*)&lB[row][sw] = vb;
    }
    __syncthreads();
    #pragma unroll
    for (int kk = 0; kk < 2; kk++){
      int cgr = kk*4 + lg;
      int ra0 = wr + l15, ra1 = wr + 16 + l15;
      int rb0 = wc + l15, rb1 = wc + 16 + l15;
      bf16x8s a0 = *(const bf16x8s*)&lA[ra0][(cgr ^ (ra0&7))*8];
      bf16x8s a1 = *(const bf16x8s*)&lA[ra1][(cgr ^ (ra1&7))*8];
      bf16x8s b0 = *(const bf16x8s*)&lB[rb0][(cgr ^ (rb0&7))*8];
      bf16x8s b1 = *(const bf16x8s*)&lB[rb1][(cgr ^ (rb1&7))*8];
      acc[0][0] = MFMA16(a0,b0,acc[0][0],0,0,0);
      acc[0][1] = MFMA16(a0,b1,acc[0][1],0,0,0);
      acc[1][0] = MFMA16(a1,b0,acc[1][0],0,0,0);
      acc[1][1] = MFMA16(a1,b1,acc[1][1],0,0,0);
    }
    __syncthreads();
  }
}

// ===== PHASE 2: x1 K-split (atomicAdd) first, then pw = qln@WcT (+m2/t2) ===
__global__ __launch_bounds__(256) void k_phase2(
    const u16* __restrict__ qln, const u16* __restrict__ wct,
    const float* __restrict__ g_k, u16* __restrict__ m2, float* __restrict__ t2s,
    const u16* __restrict__ hbuf, const u16* __restrict__ w2b,
    float* __restrict__ x1o)
{
  __shared__ __align__(16) u16 lA[64][64], lB[64][64];
  f32x4 acc[2][2] = {};
  const int bid = blockIdx.x, tid = threadIdx.x;
  const int lane = tid & 63, w = tid >> 6;
  const int wr = (w >> 1)*32, wc = (w & 1)*32;
  const int l15 = lane & 15, lg = lane >> 4;
  if (bid < 512){
    const int ks = bid >> 7;
    const int t  = bid & 127;
    const int m0 = (t >> 4)*64, n0 = (t & 15)*64;
    for (int kc = ks*512; kc < ks*512 + 512; kc += 64){
      #pragma unroll
      for (int s = 0; s < 2; s++){
        int u = tid + s*256;
        int row = u >> 3, cg = u & 7;
        int sw = (cg ^ (row & 7)) * 8;
        *(uint4*)&lA[row][sw] = *(const uint4*)(hbuf + (size_t)(m0+row)*2048 + kc + cg*8);
        uint4 vb = make_uint4(0,0,0,0);
        if (n0 + row < 1000) vb = *(const uint4*)(w2b + (size_t)(n0+row)*2048 + kc + cg*8);
        *(uint4*)&lB[row][sw] = vb;
      }
      __syncthreads();
      #pragma unroll
      for (int kk = 0; kk < 2; kk++){
        int cgr = kk*4 + lg;
        int ra0 = wr + l15, ra1 = wr + 16 + l15;
        int rb0 = wc + l15, rb1 = wc + 16 + l15;
        bf16x8s a0 = *(const bf16x8s*)&lA[ra0][(cgr ^ (ra0&7))*8];
        bf16x8s a1 = *(const bf16x8s*)&lA[ra1][(cgr ^ (ra1&7))*8];
        bf16x8s b0 = *(const bf16x8s*)&lB[rb0][(cgr ^ (rb0&7))*8];
        bf16x8s b1 = *(const bf16x8s*)&lB[rb1][(cgr ^ (rb1&7))*8];
        acc[0][0]=MFMA16(a0,b0,acc[0][0],0,0,0);
        acc[0][1]=MFMA16(a0,b1,acc[0][1],0,0,0);
        acc[1][0]=MFMA16(a1,b0,acc[1][0],0,0,0);
        acc[1][1]=MFMA16(a1,b1,acc[1][1],0,0,0);
      }
      __syncthreads();
    }
    #pragma unroll
    for (int i = 0; i < 2; i++)
      #pragma unroll
      for (int j = 0; j < 2; j++){
        int col = n0 + wc + j*16 + l15;
        if (col < 1000){
          #pragma unroll
          for (int r = 0; r < 4; r++){
            int row = m0 + wr + i*16 + lg*4 + r;
            atomicAdd(&x1o[(size_t)row*1000 + col], acc[i][j][r]);
          }
        }
      }
  } else {
    const int b = bid - 512;
    int m0 = (b>>3)*64, n0 = (b&7)*64;
    gemm_body(qln, wct, 512,512,512, m0,n0, tid, lA, lB, acc);
    #pragma unroll
    for (int i = 0; i < 2; i++){
      #pragma unroll
      for (int r = 0; r < 4; r++){
        int row = m0 + wr + i*16 + lg*4 + r;
        float part = 0.f;
        #pragma unroll
        for (int j = 0; j < 2; j++){
          int col = n0 + wc + j*16 + l15;
          float e = SCALE_C * acc[i][j][r] * g_k[col];
          m2[(size_t)row*512 + col] = f2bf(e);
          part += e;
        }
        #pragma unroll
        for (int o = 1; o < 16; o <<= 1) part += __shfl_xor(part, o);
        if (l15 == 0) atomicAdd(&t2s[row], part);
      }
    }
  }
}

// == PHASE 3: attn (r16 champion: 16-phase, conflict-free swizzle, XCD-chunked)
__global__ __launch_bounds__(512, 4) void k_attn(
    const u16* __restrict__ kxb, const u16* __restrict__ Gm,
    const u16* __restrict__ m2, const u16* __restrict__ qhat,
    const float* __restrict__ km, const float* __restrict__ kr,
    const float* __restrict__ t2s, const void* __restrict__ maskp,
    const int* __restrict__ flagp, const float* __restrict__ lsp,
    float* __restrict__ x2)
{
  __shared__ __align__(16) u16 sb[24576];   // 48KB double buffer
  __shared__ float lt2[128];
  __shared__ float lNum[128][2], lDen[128][2];
  u16* lP = sb;                              // [128][128] after main loop

  const int bid = blockIdx.x;
  const int kb = (bid & 7)*32 + ((bid >> 3) & 31);   // XCD-chunked (bijective)
  const int q0 = (bid >> 8) * 128;
  const int tid = threadIdx.x, lane = tid & 63, w = tid >> 6;
  const int wr = (w >> 1)*32, wcol = (w & 1)*64;
  const int l15 = lane & 15, lg = lane >> 4;

  const u16* KX = kxb + (size_t)kb * 65536;
  const int srow  = w*16 + (lane >> 2);
  const int sslot = (lane & 3) ^ ((srow >> 1) & 3);
  const int lofs  = w*512;                  // u16

  #define STAGE(p) do{                                                         \
    const int kc_ = (p)*32;                                                    \
    u16* b_ = sb + ((p)&1)*12288;                                              \
    gload16(KX   + (size_t)srow*512      + kc_ + sslot*8, b_ + lofs);          \
    gload16(m2   + (size_t)(q0+srow)*512 + kc_ + sslot*8, b_ + 4096 + lofs);   \
    gload16(qhat + (size_t)(q0+srow)*512 + kc_ + sslot*8, b_ + 8192 + lofs);   \
  }while(0)

  STAGE(0);   // first DMA in flight before the scalar prologue

  const int fl = *flagp;
  const float expls = __expf(lsp[0]);
  if (tid < 128) lt2[tid] = t2s[q0 + tid];

  float kmv[4], krv[4], mbv[4];
  #pragma unroll
  for (int j = 0; j < 4; j++){
    int gn = kb*128 + wcol + j*16 + l15;
    kmv[j] = km[gn]; krv[j] = kr[gn];
    int mv = fl ? ((const int*)maskp)[gn] : (int)((const unsigned char*)maskp)[gn];
    mbv[j] = mv ? -1e30f : 0.0f;
  }

  f32x4 aS[2][4] = {}, aD[2][4] = {};

  #pragma unroll
  for (int p = 0; p < 16; p++){
    if (p < 15){
      STAGE(p+1);
      asm volatile("s_waitcnt vmcnt(3)" ::: "memory");
    } else {
      asm volatile("s_waitcnt vmcnt(0)" ::: "memory");
    }
    __builtin_amdgcn_s_barrier();
    __builtin_amdgcn_sched_barrier(0);
    const u16* lb  = sb + (p&1)*12288;
    const u16* lKX = lb;
    const u16* lM2 = lb + 4096;
    const u16* lQH = lb + 8192;
    const int rA0 = wr + l15, rA1 = wr + 16 + l15;
    bf16x8s am0 = *(const bf16x8s*)&lM2[rA0*32 + ((lg ^ ((rA0>>1)&3))*8)];
    bf16x8s am1 = *(const bf16x8s*)&lM2[rA1*32 + ((lg ^ ((rA1>>1)&3))*8)];
    bf16x8s aq0 = *(const bf16x8s*)&lQH[rA0*32 + ((lg ^ ((rA0>>1)&3))*8)];
    bf16x8s aq1 = *(const bf16x8s*)&lQH[rA1*32 + ((lg ^ ((rA1>>1)&3))*8)];
    __builtin_amdgcn_s_setprio(1);
    #pragma unroll
    for (int j = 0; j < 4; j++){
      int rB = wcol + j*16 + l15;
      bf16x8s bk = *(const bf16x8s*)&lKX[rB*32 + ((lg ^ ((rB>>1)&3))*8)];
      aS[0][j] = MFMA16(am0, bk, aS[0][j], 0,0,0);
      aS[1][j] = MFMA16(am1, bk, aS[1][j], 0,0,0);
      aD[0][j] = MFMA16(aq0, bk, aD[0][j], 0,0,0);
      aD[1][j] = MFMA16(aq1, bk, aD[1][j], 0,0,0);
    }
    __builtin_amdgcn_s_setprio(0);
    __builtin_amdgcn_sched_barrier(0);
    __builtin_amdgcn_s_barrier();
  }
  __syncthreads();   // full drain before P aliases sb

  // softmax (Z cancels in x2: raw E=exp(L)) + numer partials + P write
  #pragma unroll
  for (int i = 0; i < 2; i++){
    #pragma unroll
    for (int r = 0; r < 4; r++){
      int rowl = wr + i*16 + lg*4 + r;
      float t2v = lt2[rowl];
      float sn = 0.f;
      #pragma unroll
      for (int j = 0; j < 4; j++){
        float L = krv[j]*(aS[i][j][r] - kmv[j]*t2v) + mbv[j];
        float e = __expf(L);
        aS[i][j][r] = e;
        sn += e * aD[i][j][r];
      }
      #pragma unroll
      for (int o = 1; o < 16; o <<= 1) sn += __shfl_xor(sn, o);
      if (l15 == 0) lNum[rowl][w&1] = sn;
      #pragma unroll
      for (int j = 0; j < 4; j++){
        int n = wcol + j*16 + l15;
        lP[rowl*128 + ((n>>3)^(rowl&7))*8 + (n&7)] = f2bf(aS[i][j][r]);
      }
    }
  }
  __syncthreads();

  // T = E @ G (G symmetric: row-major B-frags straight from global, L2-hot)
  f32x4 aT[2][4] = {};
  const u16* Gk = Gm + (size_t)kb * 16384;
  #pragma unroll
  for (int kk = 0; kk < 4; kk++){
    int cgr = kk*4 + lg;
    int rA0 = wr + l15, rA1 = wr + 16 + l15;
    bf16x8s p0 = *(const bf16x8s*)&lP[rA0*128 + ((cgr^(rA0&7))*8)];
    bf16x8s p1 = *(const bf16x8s*)&lP[rA1*128 + ((cgr^(rA1&7))*8)];
    #pragma unroll
    for (int j = 0; j < 4; j++){
      int mcol = wcol + j*16 + l15;
      bf16x8s bg = *(const bf16x8s*)(Gk + (size_t)mcol*128 + kk*32 + lg*8);
      aT[0][j] = MFMA16(p0, bg, aT[0][j], 0,0,0);
      aT[1][j] = MFMA16(p1, bg, aT[1][j], 0,0,0);
    }
  }
  // denom^2 partials
  #pragma unroll
  for (int i = 0; i < 2; i++){
    #pragma unroll
    for (int r = 0; r < 4; r++){
      int rowl = wr + i*16 + lg*4 + r;
      float sd = 0.f;
      #pragma unroll
      for (int j = 0; j < 4; j++) sd += aT[i][j][r] * aS[i][j][r];
      #pragma unroll
      for (int o = 1; o < 16; o <<= 1) sd += __shfl_xor(sd, o);
      if (l15 == 0) lDen[rowl][w&1] = sd;
    }
  }
  __syncthreads();

  if (tid < 128){
    float num  = lNum[tid][0] + lNum[tid][1];
    float den2 = lDen[tid][0] + lDen[tid][1];
    float den  = fmaxf(sqrtf(fmaxf(den2, 0.0f)), 1e-12f);
    x2[(size_t)(q0 + tid)*256 + kb] = expls * num / den;
  }
}

// ---------------------------------------------------------------------------
extern "C" void kernel_launch(void* const* d_in, const int* in_sizes, int n_in,
                              void* d_out, int out_size, void* d_ws, size_t ws_size,
                              hipStream_t stream)
{
  (void)in_sizes; (void)n_in; (void)out_size; (void)ws_size;
  const float* qx  = (const float*)d_in[0];
  const float* kx  = (const float*)d_in[1];
  const void*  mask= d_in[2];
  const float* lsp = (const float*)d_in[3];
  const float* g_q = (const float*)d_in[4];
  const float* b_q = (const float*)d_in[5];
  const float* g_k = (const float*)d_in[6];
  // d_in[7] (b_k): softmax-invariant per-q constant, dropped
  const float* wq  = (const float*)d_in[8];
  const float* wk  = (const float*)d_in[9];
  const float* w1  = (const float*)d_in[10];
  const float* b1  = (const float*)d_in[11];
  const float* w2  = (const float*)d_in[12];
  const float* b2  = (const float*)d_in[13];

  char* ws = (char*)d_ws;
  u16* kxb  = (u16*)(ws + OFF_KXB);
  u16* Gm   = (u16*)(ws + OFF_G);
  u16* w2b  = (u16*)(ws + OFF_W2B);
  u16* hbuf = (u16*)(ws + OFF_H);
  u16* qln  = (u16*)(ws + OFF_QLN);
  u16* qhat = (u16*)(ws + OFF_QHAT);
  u16* m2   = (u16*)(ws + OFF_M2);
  u16* wct  = (u16*)(ws + OFF_WCT);
  float* km  = (float*)(ws + OFF_KM);
  float* kr  = (float*)(ws + OFF_KR);
  float* t2s = (float*)(ws + OFF_T2);
  int*   flag= (int*)(ws + OFF_FLAG);
  float* x1o = (float*)d_out;
  float* x2o = (float*)d_out + 512*1000;

  k_phase1<<<dim3(1955), dim3(512), 0, stream>>>(
      qx, kx, (const int*)mask, g_q, b_q, wq, wk, w1, b1, w2, b2,
      kxb, km, kr, Gm, qln, qhat, wct, w2b, hbuf, t2s, flag, x1o);
  k_phase2<<<dim3(576), dim3(256), 0, stream>>>(
      qln, wct, g_k, m2, t2s, hbuf, w2b, x1o);
  k_attn<<<dim3(1024), dim3(512), 0, stream>>>(
      kxb, Gm, m2, qhat, km, kr, t2s, mask, flag, lsp, x2o);
}